// Round 1
// baseline (2304.334 us; speedup 1.0000x reference)
//
#include <hip/hip_runtime.h>
#include <hip/hip_bf16.h>

#define BB 8
#define NN 1024
#define DD 384
#define HH 6
#define HD 64
#define BN 8192          // B*N rows
#define D3 1152          // 3*D
#define D4 1536          // 4*D
#define SEC 3145728      // B*H*N*HD elems per q/k/v section

typedef __attribute__((ext_vector_type(8))) short short8;
typedef __attribute__((ext_vector_type(4))) float f32x4;

__device__ __forceinline__ float b2f(unsigned short u){
  union{unsigned int i; float f;} x; x.i=((unsigned int)u)<<16; return x.f;
}
__device__ __forceinline__ unsigned short f2b(float f){
  unsigned int u=__float_as_uint(f);
  return (unsigned short)((u + 0x7FFFu + ((u>>16)&1u))>>16);
}

// ---------------- fp32 -> bf16 weight convert ----------------
__global__ void cvt_kernel(const float* __restrict__ in, unsigned short* __restrict__ out, int n){
  int i = blockIdx.x*256 + threadIdx.x;
  if (i<n) out[i]=f2b(in[i]);
}

// ---------------- LayerNorm over D=384, one block per row ----------------
template<int OUTBF>
__global__ __launch_bounds__(128)
void ln_kernel(const float* __restrict__ in, const float* __restrict__ gg, const float* __restrict__ bb,
               float* __restrict__ outf, unsigned short* __restrict__ outb){
  int row = blockIdx.x, t = threadIdx.x;
  const float* r = in + (size_t)row*DD;
  float v0=r[t], v1=r[t+128], v2=r[t+256];
  float s=v0+v1+v2, q=v0*v0+v1*v1+v2*v2;
  #pragma unroll
  for (int o=32;o>0;o>>=1){ s+=__shfl_down(s,o); q+=__shfl_down(q,o); }
  __shared__ float ls[2], lq[2];
  if ((t&63)==0){ ls[t>>6]=s; lq[t>>6]=q; }
  __syncthreads();
  float S=ls[0]+ls[1], Q=lq[0]+lq[1];
  float mean=S*(1.0f/DD);
  float rstd=rsqrtf(Q*(1.0f/DD)-mean*mean+1e-5f);
  float o0=(v0-mean)*rstd*gg[t]+bb[t];
  float o1=(v1-mean)*rstd*gg[t+128]+bb[t+128];
  float o2=(v2-mean)*rstd*gg[t+256]+bb[t+256];
  if (OUTBF){ unsigned short* o=outb+(size_t)row*DD; o[t]=f2b(o0); o[t+128]=f2b(o1); o[t+256]=f2b(o2); }
  else      { float* o=outf+(size_t)row*DD; o[t]=o0; o[t+128]=o1; o[t+256]=o2; }
}

// ---------------- depthwise conv1d (K=7, same) + bias + LayerNorm ----------------
__global__ __launch_bounds__(128)
void conv_ln_kernel(const float* __restrict__ h2, const float* __restrict__ dww, const float* __restrict__ dwb,
                    const float* __restrict__ gg, const float* __restrict__ bb, unsigned short* __restrict__ out){
  int row=blockIdx.x, t=threadIdx.x;
  int bi=row>>10, n=row&1023;
  const float* base = h2 + (size_t)(bi<<10)*DD;
  float a[3];
  #pragma unroll
  for (int j=0;j<3;j++){
    int d=t+j*128;
    float acc=dwb[d];
    #pragma unroll
    for (int k=0;k<7;k++){
      int nn=n+k-3;
      if (nn>=0 && nn<NN) acc += dww[d*7+k]*base[(size_t)nn*DD + d];
    }
    a[j]=acc;
  }
  float s=a[0]+a[1]+a[2], q=a[0]*a[0]+a[1]*a[1]+a[2]*a[2];
  #pragma unroll
  for (int o=32;o>0;o>>=1){ s+=__shfl_down(s,o); q+=__shfl_down(q,o); }
  __shared__ float ls[2], lq[2];
  if ((t&63)==0){ ls[t>>6]=s; lq[t>>6]=q; }
  __syncthreads();
  float S=ls[0]+ls[1], Q=lq[0]+lq[1];
  float mean=S*(1.0f/DD);
  float rstd=rsqrtf(Q*(1.0f/DD)-mean*mean+1e-5f);
  unsigned short* o = out + (size_t)row*DD;
  #pragma unroll
  for (int j=0;j<3;j++){
    int d=t+j*128;
    o[d]=f2b((a[j]-mean)*rstd*gg[d]+bb[d]);
  }
}

// ---------------- bf16 MFMA GEMM: C[M,Ncols] = A[M,K] @ W[Ncols,K]^T + bias ----------------
// MODE 0: qkv scatter (fold 1/sqrt(HD) into q) -> bf16 (3,B,H,N,HD)
// MODE 1: out_f32 = resid + C   (proj / fc2)
// MODE 2: out_bf16 = gelu_exact(C)  (fc1)
template<int MODE>
__global__ __launch_bounds__(256)
void gemm_kernel(const unsigned short* __restrict__ A, const unsigned short* __restrict__ W,
                 const float* __restrict__ bias, const float* __restrict__ resid,
                 float* __restrict__ outf, unsigned short* __restrict__ outb,
                 int Kdim, int Ncols){
  int t=threadIdx.x, lane=t&63, w=t>>6;
  int bm = blockIdx.x*128 + (w>>1)*64;
  int bn = blockIdx.y*128 + (w&1)*64;
  int rm = lane&15, r16 = lane>>4;
  f32x4 acc[4][4] = {};
  const unsigned short* Ab = A + (size_t)(bm+rm)*Kdim + r16*8;
  const unsigned short* Wb = W + (size_t)(bn+rm)*Kdim + r16*8;
  for (int k0=0;k0<Kdim;k0+=32){
    short8 af[4], bf[4];
    #pragma unroll
    for (int i=0;i<4;i++) af[i]=*reinterpret_cast<const short8*>(Ab + (size_t)i*16*Kdim + k0);
    #pragma unroll
    for (int j=0;j<4;j++) bf[j]=*reinterpret_cast<const short8*>(Wb + (size_t)j*16*Kdim + k0);
    #pragma unroll
    for (int i=0;i<4;i++){
      #pragma unroll
      for (int j=0;j<4;j++){
        acc[i][j]=__builtin_amdgcn_mfma_f32_16x16x32_bf16(af[i],bf[j],acc[i][j],0,0,0);
      }
    }
  }
  #pragma unroll
  for (int i=0;i<4;i++){
    #pragma unroll
    for (int j=0;j<4;j++){
      #pragma unroll
      for (int r=0;r<4;r++){
        int row = bm + i*16 + r16*4 + r;
        int col = bn + j*16 + rm;
        float v = acc[i][j][r] + bias[col];
        if (MODE==0){
          int c = col/384; int rem = col - c*384; int hh = rem>>6, d = rem&63;
          if (c==0) v *= 0.125f;  // fold HD^-0.5 into q
          int bi = row>>10, nn = row&1023;
          outb[(size_t)c*SEC + (((size_t)(bi*6+hh))<<16) + (nn<<6) + d] = f2b(v);
        } else if (MODE==1){
          size_t idx = (size_t)row*Ncols + col;
          outf[idx] = resid[idx] + v;
        } else {
          float ge = 0.5f*v*(1.0f+erff(v*0.70710678118654752f));
          outb[(size_t)row*Ncols + col] = f2b(ge);
        }
      }
    }
  }
}

// ---------------- attention: one block per (b,n); all 6 heads; exact softmax w/ head mixes ----------------
__global__ __launch_bounds__(256)
void attn_kernel(const unsigned short* __restrict__ qkv, const float* __restrict__ tbm,
                 const float* __restrict__ tam, unsigned short* __restrict__ out){
  __shared__ float sc[HH][NN];     // mixed scores / probs row for all heads: 24KB
  __shared__ float qs[HH][HD];
  __shared__ float tb[36], ta[36];
  __shared__ float redm[4][HH], reds[4][HH];
  int blk=blockIdx.x, t=threadIdx.x;
  int b=blk>>10, n=blk&1023;
  int lane=t&63, wid=t>>6;
  for (int i=t;i<DD;i+=256){
    int h=i>>6, d=i&63;
    qs[h][d]=b2f(qkv[((size_t)(b*HH+h)<<16) + (n<<6) + d]);  // q already scaled by 0.125
  }
  if (t<36){ tb[t]=tbm[t]; ta[t]=tam[t]; }
  __syncthreads();
  const unsigned short* kbase = qkv + SEC + ((size_t)(b*HH)<<16);
  for (int m=t;m<NN;m+=256){
    float dots[HH];
    #pragma unroll
    for (int h=0;h<HH;h++){
      const unsigned short* kp = kbase + ((size_t)h<<16) + (m<<6);
      float ds=0.f;
      #pragma unroll
      for (int c8=0;c8<8;c8++){
        short8 kv=*reinterpret_cast<const short8*>(kp + c8*8);
        #pragma unroll
        for (int jj=0;jj<8;jj++) ds += qs[h][c8*8+jj]*b2f((unsigned short)kv[jj]);
      }
      dots[h]=ds;
    }
    #pragma unroll
    for (int g=0;g<HH;g++){
      float sv=0.f;
      #pragma unroll
      for (int h=0;h<HH;h++) sv += tb[g*6+h]*dots[h];
      sc[g][m]=sv;  // pre-softmax head mix
    }
  }
  __syncthreads();
  // exact softmax per mixed-head g over m (max, exp, sum)
  float lm[HH], lsum[HH];
  #pragma unroll
  for (int g=0;g<HH;g++) lm[g]=-1e30f;
  for (int m=t;m<NN;m+=256){
    #pragma unroll
    for (int g=0;g<HH;g++) lm[g]=fmaxf(lm[g],sc[g][m]);
  }
  #pragma unroll
  for (int o=32;o>0;o>>=1){
    #pragma unroll
    for (int g=0;g<HH;g++) lm[g]=fmaxf(lm[g],__shfl_xor(lm[g],o));
  }
  if (lane==0){
    #pragma unroll
    for (int g=0;g<HH;g++) redm[wid][g]=lm[g];
  }
  __syncthreads();
  float mx[HH];
  #pragma unroll
  for (int g=0;g<HH;g++) mx[g]=fmaxf(fmaxf(redm[0][g],redm[1][g]),fmaxf(redm[2][g],redm[3][g]));
  #pragma unroll
  for (int g=0;g<HH;g++) lsum[g]=0.f;
  for (int m=t;m<NN;m+=256){
    #pragma unroll
    for (int g=0;g<HH;g++){
      float e=__expf(sc[g][m]-mx[g]);
      sc[g][m]=e;
      lsum[g]+=e;
    }
  }
  #pragma unroll
  for (int o=32;o>0;o>>=1){
    #pragma unroll
    for (int g=0;g<HH;g++) lsum[g]+=__shfl_xor(lsum[g],o);
  }
  if (lane==0){
    #pragma unroll
    for (int g=0;g<HH;g++) reds[wid][g]=lsum[g];
  }
  __syncthreads();
  float inv[HH];
  #pragma unroll
  for (int g=0;g<HH;g++) inv[g]=1.0f/(reds[0][g]+reds[1][g]+reds[2][g]+reds[3][g]);
  // normalize + post-softmax head mix (each m owned by one thread)
  for (int m=t;m<NN;m+=256){
    float p[HH], pm[HH];
    #pragma unroll
    for (int h=0;h<HH;h++) p[h]=sc[h][m]*inv[h];
    #pragma unroll
    for (int g=0;g<HH;g++){
      float sv=0.f;
      #pragma unroll
      for (int h=0;h<HH;h++) sv += ta[g*6+h]*p[h];
      pm[g]=sv;
    }
    #pragma unroll
    for (int g=0;g<HH;g++) sc[g][m]=pm[g];
  }
  __syncthreads();
  // PV: thread t<192 owns (g, d0..d0+1); coalesced uint loads of v
  if (t<192){
    int g=t>>5, d0=(t&31)*2;
    const unsigned short* vp = qkv + 2*(size_t)SEC + ((size_t)(b*HH+g)<<16) + d0;
    float a0=0.f, a1=0.f;
    for (int m=0;m<NN;m++){
      float p=sc[g][m];
      unsigned int vv=*reinterpret_cast<const unsigned int*>(vp + (size_t)m*64);
      a0 += p*b2f((unsigned short)(vv&0xffffu));
      a1 += p*b2f((unsigned short)(vv>>16));
    }
    out[(size_t)blk*DD + g*64 + d0]   = f2b(a0);
    out[(size_t)blk*DD + g*64 + d0+1] = f2b(a1);
  }
}

extern "C" void kernel_launch(void* const* d_in, const int* in_sizes, int n_in,
                              void* d_out, int out_size, void* d_ws, size_t ws_size,
                              hipStream_t stream){
  const float* x      = (const float*)d_in[0];
  const float* qkv_w  = (const float*)d_in[1];
  const float* qkv_b  = (const float*)d_in[2];
  const float* proj_w = (const float*)d_in[3];
  const float* proj_b = (const float*)d_in[4];
  const float* t_before=(const float*)d_in[5];
  const float* t_after =(const float*)d_in[6];
  const float* dw_w   = (const float*)d_in[7];
  const float* dw_b   = (const float*)d_in[8];
  const float* mlp_g  = (const float*)d_in[9];
  const float* mlp_b  = (const float*)d_in[10];
  const float* n1_g   = (const float*)d_in[11];
  const float* n1_b   = (const float*)d_in[12];
  const float* n2_g   = (const float*)d_in[13];
  const float* n2_b   = (const float*)d_in[14];
  const float* fc1_w  = (const float*)d_in[15];
  const float* fc1_b  = (const float*)d_in[16];
  const float* fc2_w  = (const float*)d_in[17];
  const float* fc2_b  = (const float*)d_in[18];
  float* out = (float*)d_out;
  char* ws = (char*)d_ws;
  // workspace layout (bytes), all 256-aligned; hcln aliases hb, h2 aliases qkvb
  unsigned short* qkvwb = (unsigned short*)(ws + 0);          // 1152*384 bf16
  unsigned short* projwb= (unsigned short*)(ws + 884736);     // 384*384
  unsigned short* fc1wb = (unsigned short*)(ws + 1179648);    // 1536*384
  unsigned short* fc2wb = (unsigned short*)(ws + 2359296);    // 384*1536
  unsigned short* hb    = (unsigned short*)(ws + 3538944);    // 8192*384 bf16 (reused: hcln)
  unsigned short* qkvb  = (unsigned short*)(ws + 9830400);    // 3*SEC bf16 (reused: h2 f32)
  unsigned short* attnb = (unsigned short*)(ws + 28704768);   // 8192*384 bf16
  float*          x2    = (float*)(ws + 34996224);            // 8192*384 f32
  unsigned short* fc1o  = (unsigned short*)(ws + 47579136);   // 8192*1536 bf16
  float* h2 = (float*)qkvb;
  unsigned short* hcln = hb;

  cvt_kernel<<<(D3*DD+255)/256,256,0,stream>>>(qkv_w, qkvwb, D3*DD);
  cvt_kernel<<<(DD*DD+255)/256,256,0,stream>>>(proj_w, projwb, DD*DD);
  cvt_kernel<<<(D4*DD+255)/256,256,0,stream>>>(fc1_w, fc1wb, D4*DD);
  cvt_kernel<<<(DD*D4+255)/256,256,0,stream>>>(fc2_w, fc2wb, DD*D4);

  ln_kernel<1><<<BN,128,0,stream>>>(x, n1_g, n1_b, nullptr, hb);
  { dim3 g(BN/128, D3/128); gemm_kernel<0><<<g,256,0,stream>>>(hb, qkvwb, qkv_b, nullptr, nullptr, qkvb, DD, D3); }
  attn_kernel<<<BN,256,0,stream>>>(qkvb, t_before, t_after, attnb);
  { dim3 g(BN/128, DD/128); gemm_kernel<1><<<g,256,0,stream>>>(attnb, projwb, proj_b, x, x2, nullptr, DD, DD); }
  ln_kernel<0><<<BN,128,0,stream>>>(x2, n2_g, n2_b, h2, nullptr);
  conv_ln_kernel<<<BN,128,0,stream>>>(h2, dw_w, dw_b, mlp_g, mlp_b, hcln);
  { dim3 g(BN/128, D4/128); gemm_kernel<2><<<g,256,0,stream>>>(hcln, fc1wb, fc1_b, nullptr, nullptr, fc1o, DD, D4); }
  { dim3 g(BN/128, DD/128); gemm_kernel<1><<<g,256,0,stream>>>(fc1o, fc2wb, fc2_b, x2, out, nullptr, D4, DD); }
}

// Round 2
// 358.603 us; speedup vs baseline: 6.4259x; 6.4259x over previous
//
#include <hip/hip_runtime.h>
#include <hip/hip_bf16.h>

#define BB 8
#define NN 1024
#define DD 384
#define HH 6
#define HD 64
#define BN 8192          // B*N rows
#define D3 1152          // 3*D
#define D4 1536          // 4*D
#define SEC 3145728      // B*H*N*HD elems per q/k/v section

typedef __attribute__((ext_vector_type(8))) short short8;
typedef __attribute__((ext_vector_type(4))) float f32x4;

__device__ __forceinline__ float b2f(unsigned short u){
  union{unsigned int i; float f;} x; x.i=((unsigned int)u)<<16; return x.f;
}
__device__ __forceinline__ unsigned short f2b(float f){
  unsigned int u=__float_as_uint(f);
  return (unsigned short)((u + 0x7FFFu + ((u>>16)&1u))>>16);
}

// ---------------- fp32 -> bf16 weight convert ----------------
__global__ void cvt_kernel(const float* __restrict__ in, unsigned short* __restrict__ out, int n){
  int i = blockIdx.x*256 + threadIdx.x;
  if (i<n) out[i]=f2b(in[i]);
}

// ---------------- LayerNorm over D=384, one block per row ----------------
template<int OUTBF>
__global__ __launch_bounds__(128)
void ln_kernel(const float* __restrict__ in, const float* __restrict__ gg, const float* __restrict__ bb,
               float* __restrict__ outf, unsigned short* __restrict__ outb){
  int row = blockIdx.x, t = threadIdx.x;
  const float* r = in + (size_t)row*DD;
  float v0=r[t], v1=r[t+128], v2=r[t+256];
  float s=v0+v1+v2, q=v0*v0+v1*v1+v2*v2;
  #pragma unroll
  for (int o=32;o>0;o>>=1){ s+=__shfl_down(s,o); q+=__shfl_down(q,o); }
  __shared__ float ls[2], lq[2];
  if ((t&63)==0){ ls[t>>6]=s; lq[t>>6]=q; }
  __syncthreads();
  float S=ls[0]+ls[1], Q=lq[0]+lq[1];
  float mean=S*(1.0f/DD);
  float rstd=rsqrtf(Q*(1.0f/DD)-mean*mean+1e-5f);
  float o0=(v0-mean)*rstd*gg[t]+bb[t];
  float o1=(v1-mean)*rstd*gg[t+128]+bb[t+128];
  float o2=(v2-mean)*rstd*gg[t+256]+bb[t+256];
  if (OUTBF){ unsigned short* o=outb+(size_t)row*DD; o[t]=f2b(o0); o[t+128]=f2b(o1); o[t+256]=f2b(o2); }
  else      { float* o=outf+(size_t)row*DD; o[t]=o0; o[t+128]=o1; o[t+256]=o2; }
}

// ---------------- depthwise conv1d (K=7, same) + bias + LayerNorm ----------------
__global__ __launch_bounds__(128)
void conv_ln_kernel(const float* __restrict__ h2, const float* __restrict__ dww, const float* __restrict__ dwb,
                    const float* __restrict__ gg, const float* __restrict__ bb, unsigned short* __restrict__ out){
  int row=blockIdx.x, t=threadIdx.x;
  int bi=row>>10, n=row&1023;
  const float* base = h2 + (size_t)(bi<<10)*DD;
  float a[3];
  #pragma unroll
  for (int j=0;j<3;j++){
    int d=t+j*128;
    float acc=dwb[d];
    #pragma unroll
    for (int k=0;k<7;k++){
      int nn=n+k-3;
      if (nn>=0 && nn<NN) acc += dww[d*7+k]*base[(size_t)nn*DD + d];
    }
    a[j]=acc;
  }
  float s=a[0]+a[1]+a[2], q=a[0]*a[0]+a[1]*a[1]+a[2]*a[2];
  #pragma unroll
  for (int o=32;o>0;o>>=1){ s+=__shfl_down(s,o); q+=__shfl_down(q,o); }
  __shared__ float ls[2], lq[2];
  if ((t&63)==0){ ls[t>>6]=s; lq[t>>6]=q; }
  __syncthreads();
  float S=ls[0]+ls[1], Q=lq[0]+lq[1];
  float mean=S*(1.0f/DD);
  float rstd=rsqrtf(Q*(1.0f/DD)-mean*mean+1e-5f);
  unsigned short* o = out + (size_t)row*DD;
  #pragma unroll
  for (int j=0;j<3;j++){
    int d=t+j*128;
    o[d]=f2b((a[j]-mean)*rstd*gg[d]+bb[d]);
  }
}

// ---------------- bf16 MFMA GEMM: C[M,Ncols] = A[M,K] @ W[Ncols,K]^T + bias ----------------
// MODE 0: qkv scatter (fold 1/sqrt(HD) into q) -> bf16 (3,B,H,N,HD)
// MODE 1: out_f32 = resid + C   (proj / fc2)
// MODE 2: out_bf16 = gelu_exact(C)  (fc1)
template<int MODE>
__global__ __launch_bounds__(256)
void gemm_kernel(const unsigned short* __restrict__ A, const unsigned short* __restrict__ W,
                 const float* __restrict__ bias, const float* __restrict__ resid,
                 float* __restrict__ outf, unsigned short* __restrict__ outb,
                 int Kdim, int Ncols){
  int t=threadIdx.x, lane=t&63, w=t>>6;
  int bm = blockIdx.x*128 + (w>>1)*64;
  int bn = blockIdx.y*128 + (w&1)*64;
  int rm = lane&15, r16 = lane>>4;
  f32x4 acc[4][4] = {};
  const unsigned short* Ab = A + (size_t)(bm+rm)*Kdim + r16*8;
  const unsigned short* Wb = W + (size_t)(bn+rm)*Kdim + r16*8;
  for (int k0=0;k0<Kdim;k0+=32){
    short8 af[4], bf[4];
    #pragma unroll
    for (int i=0;i<4;i++) af[i]=*reinterpret_cast<const short8*>(Ab + (size_t)i*16*Kdim + k0);
    #pragma unroll
    for (int j=0;j<4;j++) bf[j]=*reinterpret_cast<const short8*>(Wb + (size_t)j*16*Kdim + k0);
    #pragma unroll
    for (int i=0;i<4;i++){
      #pragma unroll
      for (int j=0;j<4;j++){
        acc[i][j]=__builtin_amdgcn_mfma_f32_16x16x32_bf16(af[i],bf[j],acc[i][j],0,0,0);
      }
    }
  }
  #pragma unroll
  for (int i=0;i<4;i++){
    #pragma unroll
    for (int j=0;j<4;j++){
      #pragma unroll
      for (int r=0;r<4;r++){
        int row = bm + i*16 + r16*4 + r;
        int col = bn + j*16 + rm;
        float v = acc[i][j][r] + bias[col];
        if (MODE==0){
          int c = col/384; int rem = col - c*384; int hh = rem>>6, d = rem&63;
          if (c==0) v *= 0.125f;  // fold HD^-0.5 into q
          int bi = row>>10, nn = row&1023;
          outb[(size_t)c*SEC + (((size_t)(bi*6+hh))<<16) + (nn<<6) + d] = f2b(v);
        } else if (MODE==1){
          size_t idx = (size_t)row*Ncols + col;
          outf[idx] = resid[idx] + v;
        } else {
          float ge = 0.5f*v*(1.0f+erff(v*0.70710678118654752f));
          outb[(size_t)row*Ncols + col] = f2b(ge);
        }
      }
    }
  }
}

// ---------------- V transpose: V[bg][m][64] -> Vt[bg][64][1024] ----------------
__global__ __launch_bounds__(256)
void vt_kernel(const unsigned short* __restrict__ V, unsigned short* __restrict__ Vt){
  __shared__ unsigned short tile[64][66];
  int z = blockIdx.y, m0 = blockIdx.x*64;
  int t = threadIdx.x, c = t&63, r4 = t>>6;
  #pragma unroll
  for (int p=0;p<16;p++){
    int m = r4 + p*4;
    tile[m][c] = V[((size_t)z<<16) + ((size_t)(m0+m)<<6) + c];
  }
  __syncthreads();
  #pragma unroll
  for (int p=0;p<16;p++){
    int d = r4 + p*4;
    Vt[((size_t)z<<16) + ((size_t)d<<10) + m0 + c] = tile[c][d];
  }
}

// ---------------- QK^T batched GEMM: D[z][n][m] = q[z][n,:]·k[z][m,:]  (K=64, bf16 out) ----------------
__global__ __launch_bounds__(256)
void qk_gemm(const unsigned short* __restrict__ Q, const unsigned short* __restrict__ Kk,
             unsigned short* __restrict__ D){
  int t=threadIdx.x, lane=t&63, w=t>>6;
  int z = blockIdx.z;
  int bm = blockIdx.x*128 + (w>>1)*64;
  int bn = blockIdx.y*128 + (w&1)*64;
  int rm = lane&15, r16 = lane>>4;
  f32x4 acc[4][4] = {};
  const unsigned short* Ab = Q  + ((size_t)z<<16) + (size_t)(bm+rm)*64 + r16*8;
  const unsigned short* Bb = Kk + ((size_t)z<<16) + (size_t)(bn+rm)*64 + r16*8;
  #pragma unroll
  for (int k0=0;k0<64;k0+=32){
    short8 af[4], bf[4];
    #pragma unroll
    for (int i=0;i<4;i++) af[i]=*reinterpret_cast<const short8*>(Ab + i*16*64 + k0);
    #pragma unroll
    for (int j=0;j<4;j++) bf[j]=*reinterpret_cast<const short8*>(Bb + j*16*64 + k0);
    #pragma unroll
    for (int i=0;i<4;i++)
      #pragma unroll
      for (int j=0;j<4;j++)
        acc[i][j]=__builtin_amdgcn_mfma_f32_16x16x32_bf16(af[i],bf[j],acc[i][j],0,0,0);
  }
  #pragma unroll
  for (int i=0;i<4;i++)
    #pragma unroll
    for (int j=0;j<4;j++)
      #pragma unroll
      for (int r=0;r<4;r++){
        int row = bm + i*16 + r16*4 + r;
        int col = bn + j*16 + rm;
        D[((size_t)z<<20) + ((size_t)row<<10) + col] = f2b(acc[i][j][r]);
      }
}

// ---------------- softmax + both head mixes, in-place over D (bf16) ----------------
// block per (b_local, n); D holds dots in, mixed probs out
__global__ __launch_bounds__(256)
void sm_kernel(unsigned short* __restrict__ D, const float* __restrict__ tbm,
               const float* __restrict__ tam){
  __shared__ float sc[HH][NN];     // 24KB
  __shared__ float tb[36], ta[36];
  __shared__ float redm[4][HH], reds[4][HH];
  int blk=blockIdx.x, t=threadIdx.x;
  int bl=blk>>10, n=blk&1023;
  int lane=t&63, wid=t>>6;
  if (t<36){ tb[t]=tbm[t]; ta[t]=tam[t]; }
  __syncthreads();
  size_t base = ((size_t)bl*6)<<20;
  for (int m=t;m<NN;m+=256){
    float d[HH];
    #pragma unroll
    for (int h=0;h<HH;h++) d[h]=b2f(D[base + ((size_t)h<<20) + ((size_t)n<<10) + m]);
    #pragma unroll
    for (int g=0;g<HH;g++){
      float sv=0.f;
      #pragma unroll
      for (int h=0;h<HH;h++) sv += tb[g*6+h]*d[h];
      sc[g][m]=sv;
    }
  }
  __syncthreads();
  float lm[HH], lsum[HH];
  #pragma unroll
  for (int g=0;g<HH;g++) lm[g]=-1e30f;
  for (int m=t;m<NN;m+=256){
    #pragma unroll
    for (int g=0;g<HH;g++) lm[g]=fmaxf(lm[g],sc[g][m]);
  }
  #pragma unroll
  for (int o=32;o>0;o>>=1){
    #pragma unroll
    for (int g=0;g<HH;g++) lm[g]=fmaxf(lm[g],__shfl_xor(lm[g],o));
  }
  if (lane==0){
    #pragma unroll
    for (int g=0;g<HH;g++) redm[wid][g]=lm[g];
  }
  __syncthreads();
  float mx[HH];
  #pragma unroll
  for (int g=0;g<HH;g++) mx[g]=fmaxf(fmaxf(redm[0][g],redm[1][g]),fmaxf(redm[2][g],redm[3][g]));
  #pragma unroll
  for (int g=0;g<HH;g++) lsum[g]=0.f;
  for (int m=t;m<NN;m+=256){
    #pragma unroll
    for (int g=0;g<HH;g++){
      float e=__expf(sc[g][m]-mx[g]);
      sc[g][m]=e;
      lsum[g]+=e;
    }
  }
  #pragma unroll
  for (int o=32;o>0;o>>=1){
    #pragma unroll
    for (int g=0;g<HH;g++) lsum[g]+=__shfl_xor(lsum[g],o);
  }
  if (lane==0){
    #pragma unroll
    for (int g=0;g<HH;g++) reds[wid][g]=lsum[g];
  }
  __syncthreads();
  float inv[HH];
  #pragma unroll
  for (int g=0;g<HH;g++) inv[g]=1.0f/(reds[0][g]+reds[1][g]+reds[2][g]+reds[3][g]);
  for (int m=t;m<NN;m+=256){
    float p[HH];
    #pragma unroll
    for (int h=0;h<HH;h++) p[h]=sc[h][m]*inv[h];
    #pragma unroll
    for (int g=0;g<HH;g++){
      float sv=0.f;
      #pragma unroll
      for (int h=0;h<HH;h++) sv += ta[g*6+h]*p[h];
      D[base + ((size_t)g<<20) + ((size_t)n<<10) + m] = f2b(sv);
    }
  }
}

// ---------------- PV batched GEMM: out[n, g*64+d] = sum_m P[z][n,m] Vt[z][d,m] ----------------
__global__ __launch_bounds__(256)
void pv_gemm(const unsigned short* __restrict__ P, const unsigned short* __restrict__ Vt,
             unsigned short* __restrict__ outp){
  int t=threadIdx.x, lane=t&63, w=t>>6;
  int z = blockIdx.y;
  int bm = blockIdx.x*128 + w*32;
  int rm = lane&15, r16 = lane>>4;
  f32x4 acc[2][4] = {};
  const unsigned short* Ab = P  + ((size_t)z<<20) + (size_t)(bm+rm)*1024 + r16*8;
  const unsigned short* Bb = Vt + ((size_t)z<<16) + ((size_t)rm<<10) + r16*8;
  for (int k0=0;k0<1024;k0+=32){
    short8 af[2], bf[4];
    #pragma unroll
    for (int i=0;i<2;i++) af[i]=*reinterpret_cast<const short8*>(Ab + i*16*1024 + k0);
    #pragma unroll
    for (int j=0;j<4;j++) bf[j]=*reinterpret_cast<const short8*>(Bb + j*16*1024 + k0);
    #pragma unroll
    for (int i=0;i<2;i++)
      #pragma unroll
      for (int j=0;j<4;j++)
        acc[i][j]=__builtin_amdgcn_mfma_f32_16x16x32_bf16(af[i],bf[j],acc[i][j],0,0,0);
  }
  int bl = z/6, g = z - bl*6;
  #pragma unroll
  for (int i=0;i<2;i++)
    #pragma unroll
    for (int j=0;j<4;j++)
      #pragma unroll
      for (int r=0;r<4;r++){
        int n = bm + i*16 + r16*4 + r;
        int d = j*16 + rm;
        outp[((size_t)((bl<<10)|n))*DD + g*64 + d] = f2b(acc[i][j][r]);
      }
}

extern "C" void kernel_launch(void* const* d_in, const int* in_sizes, int n_in,
                              void* d_out, int out_size, void* d_ws, size_t ws_size,
                              hipStream_t stream){
  const float* x      = (const float*)d_in[0];
  const float* qkv_w  = (const float*)d_in[1];
  const float* qkv_b  = (const float*)d_in[2];
  const float* proj_w = (const float*)d_in[3];
  const float* proj_b = (const float*)d_in[4];
  const float* t_before=(const float*)d_in[5];
  const float* t_after =(const float*)d_in[6];
  const float* dw_w   = (const float*)d_in[7];
  const float* dw_b   = (const float*)d_in[8];
  const float* mlp_g  = (const float*)d_in[9];
  const float* mlp_b  = (const float*)d_in[10];
  const float* n1_g   = (const float*)d_in[11];
  const float* n1_b   = (const float*)d_in[12];
  const float* n2_g   = (const float*)d_in[13];
  const float* n2_b   = (const float*)d_in[14];
  const float* fc1_w  = (const float*)d_in[15];
  const float* fc1_b  = (const float*)d_in[16];
  const float* fc2_w  = (const float*)d_in[17];
  const float* fc2_b  = (const float*)d_in[18];
  float* out = (float*)d_out;
  char* ws = (char*)d_ws;
  // layout (bytes):
  unsigned short* qkvwb = (unsigned short*)(ws + 0);          // 1152*384 bf16
  unsigned short* projwb= (unsigned short*)(ws + 884736);
  unsigned short* fc1wb = (unsigned short*)(ws + 1179648);
  unsigned short* fc2wb = (unsigned short*)(ws + 2359296);
  unsigned short* hb    = (unsigned short*)(ws + 3538944);    // 8192*384 bf16 (reuse: hcln)
  unsigned short* qkvb  = (unsigned short*)(ws + 9830400);    // 3*SEC bf16 (reuse: h2 f32)
  unsigned short* Vt    = (unsigned short*)(ws + 28704768);   // 48*64*1024 bf16
  unsigned short* Dp    = (unsigned short*)(ws + 34996224);   // 24M bf16 per chunk (reuse: fc1o)
  unsigned short* attnb = (unsigned short*)(ws + 85327872);   // 8192*384 bf16
  float*          x2    = (float*)(ws + 91619328);            // 8192*384 f32
  float* h2 = (float*)qkvb;
  unsigned short* hcln = hb;
  unsigned short* fc1o = Dp;

  cvt_kernel<<<(D3*DD+255)/256,256,0,stream>>>(qkv_w, qkvwb, D3*DD);
  cvt_kernel<<<(DD*DD+255)/256,256,0,stream>>>(proj_w, projwb, DD*DD);
  cvt_kernel<<<(D4*DD+255)/256,256,0,stream>>>(fc1_w, fc1wb, D4*DD);
  cvt_kernel<<<(DD*D4+255)/256,256,0,stream>>>(fc2_w, fc2wb, DD*D4);

  ln_kernel<1><<<BN,128,0,stream>>>(x, n1_g, n1_b, nullptr, hb);
  { dim3 g(BN/128, D3/128); gemm_kernel<0><<<g,256,0,stream>>>(hb, qkvwb, qkv_b, nullptr, nullptr, qkvb, DD, D3); }
  { dim3 g(NN/64, 48); vt_kernel<<<g,256,0,stream>>>(qkvb + 2*(size_t)SEC, Vt); }
  for (int c=0;c<2;c++){
    size_t qoff = ((size_t)(c*24))<<16;
    { dim3 g(8,8,24); qk_gemm<<<g,256,0,stream>>>(qkvb + qoff, qkvb + SEC + qoff, Dp); }
    sm_kernel<<<4096,256,0,stream>>>(Dp, t_before, t_after);
    { dim3 g(8,24); pv_gemm<<<g,256,0,stream>>>(Dp, Vt + qoff, attnb + (size_t)c*4*1024*DD); }
  }
  { dim3 g(BN/128, DD/128); gemm_kernel<1><<<g,256,0,stream>>>(attnb, projwb, proj_b, x, x2, nullptr, DD, DD); }
  ln_kernel<0><<<BN,128,0,stream>>>(x2, n2_g, n2_b, h2, nullptr);
  conv_ln_kernel<<<BN,128,0,stream>>>(h2, dw_w, dw_b, mlp_g, mlp_b, hcln);
  { dim3 g(BN/128, D4/128); gemm_kernel<2><<<g,256,0,stream>>>(hcln, fc1wb, fc1_b, nullptr, nullptr, fc1o, DD, D4); }
  { dim3 g(BN/128, DD/128); gemm_kernel<1><<<g,256,0,stream>>>(fc1o, fc2wb, fc2_b, x2, out, nullptr, D4, DD); }
}